// Round 2
// baseline (985.580 us; speedup 1.0000x reference)
//
#include <hip/hip_runtime.h>
#include <math.h>

// Problem constants (fixed by the reference)
#define B_N  16384
#define T_N  3
#define D_N  512
#define G_N  4
#define NE_N 4
#define H_N  512
#define E_N  256
#define GH_N 256
#define K16  16      // G*NE experts
#define TH_N 128
#define TO_N 64

typedef __attribute__((ext_vector_type(8))) short short8;
typedef __attribute__((ext_vector_type(4))) float floatx4;

__device__ __forceinline__ unsigned short f2bf(float f) {
    union { float f; unsigned u; } v; v.f = f;
    unsigned r = (v.u + 0x7fffu + ((v.u >> 16) & 1u)) >> 16;
    return (unsigned short)r;
}
__device__ __forceinline__ float bf2f(unsigned short h) {
    union { unsigned u; float f; } v; v.u = ((unsigned)h) << 16;
    return v.f;
}
__device__ __forceinline__ unsigned pack2(float lo, float hi) {
    return ((unsigned)f2bf(hi) << 16) | (unsigned)f2bf(lo);
}

typedef const __attribute__((address_space(1))) void gvoid_t;
typedef __attribute__((address_space(3))) void lvoid_t;

#if __has_builtin(__builtin_amdgcn_global_load_lds)
#define HAVE_GLL 1
__device__ __forceinline__ void load_lds16(const void* g, void* l) {
    __builtin_amdgcn_global_load_lds((gvoid_t*)g, (lvoid_t*)l, 16, 0, 0);
}
#else
#define HAVE_GLL 0
#endif

// ---------------------------------------------------------------------------
// Input cast: x -> bf16 [BC][G*D]; gin = x[:,1+t]+x[:,0] -> bf16 [BC][T*D]
// ---------------------------------------------------------------------------
__global__ __launch_bounds__(256) void convert_inputs(
    const float* __restrict__ x, unsigned short* __restrict__ xb,
    unsigned short* __restrict__ ginb)
{
    const long b = blockIdx.x;
    const int tid = threadIdx.x;           // 256 threads, 2 floats each per g
    const float* xr = x + b * (G_N * D_N);
    unsigned short* xo = xb + b * (G_N * D_N);
    unsigned short* go = ginb + b * (T_N * D_N);
    float2 v0 = *(const float2*)&xr[tid * 2];
    *(unsigned*)&xo[tid * 2] = pack2(v0.x, v0.y);
    #pragma unroll
    for (int g = 1; g < G_N; ++g) {
        float2 v = *(const float2*)&xr[g * D_N + tid * 2];
        *(unsigned*)&xo[g * D_N + tid * 2] = pack2(v.x, v.y);
        *(unsigned*)&go[(g - 1) * D_N + tid * 2] = pack2(v.x + v0.x, v.y + v0.y);
    }
}

// ---------------------------------------------------------------------------
// Weight transpose + cast: in fp32 [Z][K][N] -> out bf16 [Z][N][K]
// ---------------------------------------------------------------------------
__global__ __launch_bounds__(256) void transpose_w(
    const float* __restrict__ in, unsigned short* __restrict__ out, int K, int N)
{
    __shared__ float tile[32][33];
    const int tx = threadIdx.x, ty = threadIdx.y;      // block (32,8)
    const long zo = (long)blockIdx.z * K * N;
    const int n0 = blockIdx.x * 32, k0 = blockIdx.y * 32;
    #pragma unroll
    for (int i = 0; i < 4; ++i)
        tile[ty + 8 * i][tx] = in[zo + (long)(k0 + ty + 8 * i) * N + n0 + tx];
    __syncthreads();
    #pragma unroll
    for (int i = 0; i < 4; ++i)
        out[zo + (long)(n0 + ty + 8 * i) * K + k0 + tx] = f2bf(tile[tx][ty + 8 * i]);
}

// ---------------------------------------------------------------------------
// bf16 MFMA GEMM: C[z] = act(A[z] (MxK) * Bt[z]^T (N-major NxK) + bias[z])
// 128x128 tile, BK=32, 256 threads = 4 waves (2x2 of 64x64), m97 structure.
// ---------------------------------------------------------------------------
template<int RELU>
__global__ __launch_bounds__(256) void gemm_bf16(
    const unsigned short* __restrict__ A, int lda, int a_zoff,
    const unsigned short* __restrict__ Bt, int bt_zoff,
    const float* __restrict__ bias, int bias_zoff,
    unsigned short* __restrict__ C, int ldc, int c_zoff, int K)
{
    __shared__ __align__(16) unsigned short As[128 * 32];
    __shared__ __align__(16) unsigned short Bs[128 * 32];
    const int tid = threadIdx.x;
    const int z = blockIdx.z;
    const long m0 = (long)blockIdx.x * 128;
    const long n0 = (long)blockIdx.y * 128;
    const unsigned short* Ab = A + (long)z * a_zoff + m0 * lda;
    const unsigned short* Bb = Bt + (long)z * bt_zoff + n0 * K;
    const int lane16 = tid & 15;
    const int quad = (tid & 63) >> 4;
    const int wave = tid >> 6;
    const int wm = (wave >> 1) * 64;
    const int wn = (wave & 1) * 64;
    const int srow = tid >> 2;             // staging row (0..63)
    const int scol = (tid & 3) * 8;        // staging col (0,8,16,24)

    floatx4 acc[4][4] = {};

    for (int k0 = 0; k0 < K; k0 += 32) {
#if HAVE_GLL
        load_lds16(Ab + (long)srow * lda + k0 + scol, &As[tid * 8]);
        load_lds16(Ab + (long)(srow + 64) * lda + k0 + scol, &As[2048 + tid * 8]);
        load_lds16(Bb + (long)srow * K + k0 + scol, &Bs[tid * 8]);
        load_lds16(Bb + (long)(srow + 64) * K + k0 + scol, &Bs[2048 + tid * 8]);
#else
        *(uint4*)&As[tid * 8] = *(const uint4*)(Ab + (long)srow * lda + k0 + scol);
        *(uint4*)&As[2048 + tid * 8] = *(const uint4*)(Ab + (long)(srow + 64) * lda + k0 + scol);
        *(uint4*)&Bs[tid * 8] = *(const uint4*)(Bb + (long)srow * K + k0 + scol);
        *(uint4*)&Bs[2048 + tid * 8] = *(const uint4*)(Bb + (long)(srow + 64) * K + k0 + scol);
#endif
        __syncthreads();
        short8 a[4], b[4];
        #pragma unroll
        for (int mi = 0; mi < 4; ++mi)
            a[mi] = *(const short8*)&As[(wm + mi * 16 + lane16) * 32 + quad * 8];
        #pragma unroll
        for (int ni = 0; ni < 4; ++ni)
            b[ni] = *(const short8*)&Bs[(wn + ni * 16 + lane16) * 32 + quad * 8];
        #pragma unroll
        for (int mi = 0; mi < 4; ++mi)
            #pragma unroll
            for (int ni = 0; ni < 4; ++ni)
                acc[mi][ni] = __builtin_amdgcn_mfma_f32_16x16x32_bf16(
                    a[mi], b[ni], acc[mi][ni], 0, 0, 0);
        __syncthreads();
    }

    unsigned short* Cb = C + (long)z * c_zoff + m0 * ldc + n0;
    const float* bb = bias + (long)z * bias_zoff + n0;
    #pragma unroll
    for (int mi = 0; mi < 4; ++mi) {
        #pragma unroll
        for (int ni = 0; ni < 4; ++ni) {
            const int col = wn + ni * 16 + lane16;
            const float bv = bb[col];
            #pragma unroll
            for (int r = 0; r < 4; ++r) {
                const int row = wm + mi * 16 + quad * 4 + r;
                float v = acc[mi][ni][r] + bv;
                if (RELU) v = fmaxf(v, 0.0f);
                Cb[(long)row * ldc + col] = f2bf(v);
            }
        }
    }
}

// ---------------------------------------------------------------------------
// Gate layer 2 + softmax: gw[b][t][k] = softmax_k(gh[b][t]·W2[t] + b2[t])
// Block: 64 b-rows for one t. 256 threads.
// ---------------------------------------------------------------------------
__global__ __launch_bounds__(256) void gate2_softmax(
    const unsigned short* __restrict__ gh, const float* __restrict__ W2,
    const float* __restrict__ b2, float* __restrict__ gw)
{
    const int t = blockIdx.y;
    const long b0 = (long)blockIdx.x * 64;
    const int tid = threadIdx.x;
    __shared__ __align__(16) unsigned short ghs[64 * 256];
    __shared__ float ls[64 * 16];
    #pragma unroll
    for (int it = 0; it < 8; ++it) {
        int seg = it * 256 + tid;
        int row = seg >> 5;
        int col = (seg & 31) * 8;
        *(uint4*)&ghs[seg * 8] =
            *(const uint4*)&gh[(b0 + row) * (T_N * GH_N) + (long)t * GH_N + col];
    }
    __syncthreads();
    const float* W2t = W2 + (long)t * GH_N * K16;
    #pragma unroll
    for (int it = 0; it < 4; ++it) {
        int o = it * 256 + tid;
        int b = o >> 4, k = o & 15;
        float acc = b2[t * K16 + k];
        #pragma unroll 8
        for (int h = 0; h < GH_N; ++h)
            acc += bf2f(ghs[b * 256 + h]) * W2t[h * K16 + k];
        ls[o] = acc;
    }
    __syncthreads();
    if (tid < 64) {
        float m = -1e30f;
        #pragma unroll
        for (int k = 0; k < 16; ++k) m = fmaxf(m, ls[tid * 16 + k]);
        float e[16], s = 0.f;
        #pragma unroll
        for (int k = 0; k < 16; ++k) { e[k] = expf(ls[tid * 16 + k] - m); s += e[k]; }
        const float inv = 1.0f / s;
        float* gwp = gw + (b0 + tid) * (T_N * K16) + (long)t * K16;
        #pragma unroll
        for (int k = 0; k < 16; ++k) gwp[k] = e[k] * inv;
    }
}

// ---------------------------------------------------------------------------
// agg + towers: per block 4 batch rows.
// agg[t] = sum_k gw[t][k]*emb[k]; th = relu(agg·tW1+tb1); out = th·tW2+tb2
// ---------------------------------------------------------------------------
__global__ __launch_bounds__(256) void agg_tower(
    const unsigned short* __restrict__ emb, const float* __restrict__ gw,
    const float* __restrict__ tw1, const float* __restrict__ tb1,
    const float* __restrict__ tw2, const float* __restrict__ tb2,
    float* __restrict__ out)
{
    const long b0 = (long)blockIdx.x * 4;
    const int tid = threadIdx.x;
    __shared__ __align__(16) unsigned short embs[4 * 4096];  // 32 KB
    __shared__ float gws[4 * 48];
    __shared__ float aggs[12 * 256];           // 12 KB
    __shared__ float ths[12 * 128];            // 6 KB
    #pragma unroll
    for (int it = 0; it < 8; ++it) {
        int seg = it * 256 + tid;
        int bb = seg >> 9, off = (seg & 511) * 8;
        *(uint4*)&embs[bb * 4096 + off] = *(const uint4*)&emb[(b0 + bb) * 4096 + off];
    }
    if (tid < 192) gws[tid] = gw[b0 * 48 + tid];
    __syncthreads();
    #pragma unroll
    for (int it = 0; it < 12; ++it) {
        int o = it * 256 + tid;
        int e = o & 255, q = o >> 8;      // q = bb*3 + t
        int t = q % 3, bb = q / 3;
        float s = 0.f;
        #pragma unroll
        for (int k = 0; k < 16; ++k)
            s += gws[bb * 48 + t * 16 + k] * bf2f(embs[bb * 4096 + k * 256 + e]);
        aggs[q * 256 + e] = s;
    }
    __syncthreads();
    for (int p = tid; p < 384; p += 256) {       // (t,h) pairs; all 4 bb per thread
        int t = p >> 7, h = p & 127;
        float a0 = 0, a1 = 0, a2 = 0, a3 = 0;
        const float* w = tw1 + (long)t * E_N * TH_N + h;
        #pragma unroll 4
        for (int e = 0; e < E_N; ++e) {
            float wv = w[e * TH_N];
            a0 += aggs[(0 * 3 + t) * 256 + e] * wv;
            a1 += aggs[(1 * 3 + t) * 256 + e] * wv;
            a2 += aggs[(2 * 3 + t) * 256 + e] * wv;
            a3 += aggs[(3 * 3 + t) * 256 + e] * wv;
        }
        float bv = tb1[t * TH_N + h];
        ths[(0 * 3 + t) * 128 + h] = fmaxf(a0 + bv, 0.f);
        ths[(1 * 3 + t) * 128 + h] = fmaxf(a1 + bv, 0.f);
        ths[(2 * 3 + t) * 128 + h] = fmaxf(a2 + bv, 0.f);
        ths[(3 * 3 + t) * 128 + h] = fmaxf(a3 + bv, 0.f);
    }
    __syncthreads();
    if (tid < 192) {                              // (t,o2) pairs
        int t = tid >> 6, o2 = tid & 63;
        float a0 = 0, a1 = 0, a2 = 0, a3 = 0;
        const float* w = tw2 + (long)t * TH_N * TO_N + o2;
        #pragma unroll 4
        for (int h = 0; h < TH_N; ++h) {
            float wv = w[h * TO_N];
            a0 += ths[(0 * 3 + t) * 128 + h] * wv;
            a1 += ths[(1 * 3 + t) * 128 + h] * wv;
            a2 += ths[(2 * 3 + t) * 128 + h] * wv;
            a3 += ths[(3 * 3 + t) * 128 + h] * wv;
        }
        float bv = tb2[t * TO_N + o2];
        out[(b0 + 0) * 192 + t * 64 + o2] = a0 + bv;
        out[(b0 + 1) * 192 + t * 64 + o2] = a1 + bv;
        out[(b0 + 2) * 192 + t * 64 + o2] = a2 + bv;
        out[(b0 + 3) * 192 + t * 64 + o2] = a3 + bv;
    }
}

// ---------------------------------------------------------------------------
extern "C" void kernel_launch(void* const* d_in, const int* in_sizes, int n_in,
                              void* d_out, int out_size, void* d_ws, size_t ws_size,
                              hipStream_t stream)
{
    const float* x   = (const float*)d_in[0];
    const float* eW1 = (const float*)d_in[1];
    const float* eb1 = (const float*)d_in[2];
    const float* eW2 = (const float*)d_in[3];
    const float* eb2 = (const float*)d_in[4];
    const float* gW1 = (const float*)d_in[5];
    const float* gb1 = (const float*)d_in[6];
    const float* gW2 = (const float*)d_in[7];
    const float* gb2 = (const float*)d_in[8];
    const float* tW1 = (const float*)d_in[9];
    const float* tb1 = (const float*)d_in[10];
    const float* tW2 = (const float*)d_in[11];
    const float* tb2 = (const float*)d_in[12];
    float* out = (float*)d_out;

    char* ws = (char*)d_ws;
    // Persistent (whole-call) weight buffers: 13,369,344 B total
    unsigned short* W1t = (unsigned short*)(ws + 0);          // [16][512][512] bf16, 8 MB
    unsigned short* W2t = (unsigned short*)(ws + 8388608);    // [16][256][512] bf16, 4 MB
    unsigned short* G1t = (unsigned short*)(ws + 12582912);   // [3][256][512] bf16, 768 KB
    const size_t WFIX = 13369344;

    // Per-chunk scratch: 33,472 B per batch row. Pick largest chunk that fits.
    const long per_row = 33472;
    long BC = 0;
    for (long cand = 16384; cand >= 256; cand >>= 1) {
        if (WFIX + (size_t)(cand * per_row) <= ws_size) { BC = cand; break; }
    }
    if (BC == 0) return;  // workspace too small — fail cleanly, not with a fault

    char* p = ws + WFIX;
    unsigned short* xb   = (unsigned short*)p; p += BC * 2048 * 2;  // [BC][G*D]
    unsigned short* ginb = (unsigned short*)p; p += BC * 1536 * 2;  // [BC][T*D]
    unsigned short* h1   = (unsigned short*)p; p += BC * 8192 * 2;  // [BC][16*H]
    unsigned short* embb = (unsigned short*)p; p += BC * 4096 * 2;  // [BC][16*E]
    unsigned short* gh   = (unsigned short*)p; p += BC * 768 * 2;   // [BC][T*GH]
    float*          gw   = (float*)p;                               // [BC][T][16]

    // Weight transposes (once per call)
    transpose_w<<<dim3(16, 16, 16), dim3(32, 8), 0, stream>>>(eW1, W1t, 512, 512);
    transpose_w<<<dim3(8, 16, 16), dim3(32, 8), 0, stream>>>(eW2, W2t, 512, 256);
    transpose_w<<<dim3(8, 16, 3), dim3(32, 8), 0, stream>>>(gW1, G1t, 512, 256);

    const long n_chunks = B_N / BC;
    for (long c = 0; c < n_chunks; ++c) {
        const float* xc = x + c * BC * (G_N * D_N);
        float* outc = out + c * BC * (T_N * TO_N);

        convert_inputs<<<BC, 256, 0, stream>>>(xc, xb, ginb);
        // expert layer 1: per g: [BC x 512] @ [512 x 2048] -> relu -> h1 (bf16)
        gemm_bf16<1><<<dim3(BC / 128, 16, 4), 256, 0, stream>>>(
            xb, 2048, 512, W1t, 1048576, eb1, 2048, h1, 8192, 2048, 512);
        // gate layer 1: per t: [BC x 512] @ [512 x 256] -> relu -> gh (bf16)
        gemm_bf16<1><<<dim3(BC / 128, 2, 3), 256, 0, stream>>>(
            ginb, 1536, 512, G1t, 131072, gb1, 256, gh, 768, 256, 512);
        // gate layer 2 + softmax -> gw (fp32)
        gate2_softmax<<<dim3(BC / 64, 3), 256, 0, stream>>>(gh, gW2, gb2, gw);
        // expert layer 2: per (g,n): [BC x 512] @ [512 x 256] -> emb (bf16)
        gemm_bf16<0><<<dim3(BC / 128, 2, 16), 256, 0, stream>>>(
            h1, 8192, 512, W2t, 131072, eb2, 256, embb, 4096, 256, 512);
        // agg + towers -> out (fp32)
        agg_tower<<<BC / 4, 256, 0, stream>>>(embb, gw, tW1, tb1, tW2, tb2, outc);
    }
}

// Round 3
// 783.437 us; speedup vs baseline: 1.2580x; 1.2580x over previous
//
#include <hip/hip_runtime.h>
#include <math.h>

// Problem constants (fixed by the reference)
#define B_N  16384
#define T_N  3
#define D_N  512
#define G_N  4
#define NE_N 4
#define H_N  512
#define E_N  256
#define GH_N 256
#define K16  16      // G*NE experts
#define TH_N 128
#define TO_N 64

typedef __attribute__((ext_vector_type(8))) short short8;
typedef __attribute__((ext_vector_type(4))) float floatx4;

__device__ __forceinline__ unsigned short f2bf(float f) {
    union { float f; unsigned u; } v; v.f = f;
    unsigned r = (v.u + 0x7fffu + ((v.u >> 16) & 1u)) >> 16;
    return (unsigned short)r;
}
__device__ __forceinline__ float bf2f(unsigned short h) {
    union { unsigned u; float f; } v; v.u = ((unsigned)h) << 16;
    return v.f;
}
__device__ __forceinline__ unsigned pack2(float lo, float hi) {
    return ((unsigned)f2bf(hi) << 16) | (unsigned)f2bf(lo);
}

typedef const __attribute__((address_space(1))) void gvoid_t;
typedef __attribute__((address_space(3))) void lvoid_t;

#if __has_builtin(__builtin_amdgcn_global_load_lds)
#define HAVE_GLL 1
__device__ __forceinline__ void load_lds16(const void* g, void* l) {
    __builtin_amdgcn_global_load_lds((gvoid_t*)g, (lvoid_t*)l, 16, 0, 0);
}
#else
#define HAVE_GLL 0
#endif

// ---------------------------------------------------------------------------
// Input cast: x -> bf16 [BC][G*D]; gin = x[:,1+t]+x[:,0] -> bf16 [BC][T*D]
// ---------------------------------------------------------------------------
__global__ __launch_bounds__(256) void convert_inputs(
    const float* __restrict__ x, unsigned short* __restrict__ xb,
    unsigned short* __restrict__ ginb)
{
    const long b = blockIdx.x;
    const int tid = threadIdx.x;           // 256 threads, 2 floats each per g
    const float* xr = x + b * (G_N * D_N);
    unsigned short* xo = xb + b * (G_N * D_N);
    unsigned short* go = ginb + b * (T_N * D_N);
    float2 v0 = *(const float2*)&xr[tid * 2];
    *(unsigned*)&xo[tid * 2] = pack2(v0.x, v0.y);
    #pragma unroll
    for (int g = 1; g < G_N; ++g) {
        float2 v = *(const float2*)&xr[g * D_N + tid * 2];
        *(unsigned*)&xo[g * D_N + tid * 2] = pack2(v.x, v.y);
        *(unsigned*)&go[(g - 1) * D_N + tid * 2] = pack2(v.x + v0.x, v.y + v0.y);
    }
}

// ---------------------------------------------------------------------------
// Weight transpose + cast: in fp32 [Z][K][N] -> out bf16 [Z][N][K]
// ---------------------------------------------------------------------------
__global__ __launch_bounds__(256) void transpose_w(
    const float* __restrict__ in, unsigned short* __restrict__ out, int K, int N)
{
    __shared__ float tile[32][33];
    const int tx = threadIdx.x, ty = threadIdx.y;      // block (32,8)
    const long zo = (long)blockIdx.z * K * N;
    const int n0 = blockIdx.x * 32, k0 = blockIdx.y * 32;
    #pragma unroll
    for (int i = 0; i < 4; ++i)
        tile[ty + 8 * i][tx] = in[zo + (long)(k0 + ty + 8 * i) * N + n0 + tx];
    __syncthreads();
    #pragma unroll
    for (int i = 0; i < 4; ++i)
        out[zo + (long)(n0 + ty + 8 * i) * K + k0 + tx] = f2bf(tile[tx][ty + 8 * i]);
}

// ---------------------------------------------------------------------------
// bf16 MFMA GEMM: C[z] = act(A[z] (MxK) * Bt[z]^T (N-major NxK) + bias[z])
// 128x128 tile, BK=32, 256 threads = 4 waves (2x2 of 64x64), m97 structure.
// ---------------------------------------------------------------------------
template<int RELU>
__global__ __launch_bounds__(256) void gemm_bf16(
    const unsigned short* __restrict__ A, int lda, int a_zoff,
    const unsigned short* __restrict__ Bt, int bt_zoff,
    const float* __restrict__ bias, int bias_zoff,
    unsigned short* __restrict__ C, int ldc, int c_zoff, int K)
{
    __shared__ __align__(16) unsigned short As[128 * 32];
    __shared__ __align__(16) unsigned short Bs[128 * 32];
    const int tid = threadIdx.x;
    const int z = blockIdx.z;
    const long m0 = (long)blockIdx.x * 128;
    const long n0 = (long)blockIdx.y * 128;
    const unsigned short* Ab = A + (long)z * a_zoff + m0 * lda;
    const unsigned short* Bb = Bt + (long)z * bt_zoff + n0 * K;
    const int lane16 = tid & 15;
    const int quad = (tid & 63) >> 4;
    const int wave = tid >> 6;
    const int wm = (wave >> 1) * 64;
    const int wn = (wave & 1) * 64;
    const int srow = tid >> 2;             // staging row (0..63)
    const int scol = (tid & 3) * 8;        // staging col (0,8,16,24)

    floatx4 acc[4][4] = {};

    for (int k0 = 0; k0 < K; k0 += 32) {
#if HAVE_GLL
        load_lds16(Ab + (long)srow * lda + k0 + scol, &As[tid * 8]);
        load_lds16(Ab + (long)(srow + 64) * lda + k0 + scol, &As[2048 + tid * 8]);
        load_lds16(Bb + (long)srow * K + k0 + scol, &Bs[tid * 8]);
        load_lds16(Bb + (long)(srow + 64) * K + k0 + scol, &Bs[2048 + tid * 8]);
#else
        *(uint4*)&As[tid * 8] = *(const uint4*)(Ab + (long)srow * lda + k0 + scol);
        *(uint4*)&As[2048 + tid * 8] = *(const uint4*)(Ab + (long)(srow + 64) * lda + k0 + scol);
        *(uint4*)&Bs[tid * 8] = *(const uint4*)(Bb + (long)srow * K + k0 + scol);
        *(uint4*)&Bs[2048 + tid * 8] = *(const uint4*)(Bb + (long)(srow + 64) * K + k0 + scol);
#endif
        __syncthreads();
        short8 a[4], b[4];
        #pragma unroll
        for (int mi = 0; mi < 4; ++mi)
            a[mi] = *(const short8*)&As[(wm + mi * 16 + lane16) * 32 + quad * 8];
        #pragma unroll
        for (int ni = 0; ni < 4; ++ni)
            b[ni] = *(const short8*)&Bs[(wn + ni * 16 + lane16) * 32 + quad * 8];
        #pragma unroll
        for (int mi = 0; mi < 4; ++mi)
            #pragma unroll
            for (int ni = 0; ni < 4; ++ni)
                acc[mi][ni] = __builtin_amdgcn_mfma_f32_16x16x32_bf16(
                    a[mi], b[ni], acc[mi][ni], 0, 0, 0);
        __syncthreads();
    }

    unsigned short* Cb = C + (long)z * c_zoff + m0 * ldc + n0;
    const float* bb = bias + (long)z * bias_zoff + n0;
    #pragma unroll
    for (int mi = 0; mi < 4; ++mi) {
        #pragma unroll
        for (int ni = 0; ni < 4; ++ni) {
            const int col = wn + ni * 16 + lane16;
            const float bv = bb[col];
            #pragma unroll
            for (int r = 0; r < 4; ++r) {
                const int row = wm + mi * 16 + quad * 4 + r;
                float v = acc[mi][ni][r] + bv;
                if (RELU) v = fmaxf(v, 0.0f);
                Cb[(long)row * ldc + col] = f2bf(v);
            }
        }
    }
}

// ---------------------------------------------------------------------------
// Gate layer 2 + softmax: gw[b][t][k] = softmax_k(gh[b][t]·W2[t] + b2[t])
// Block: 64 b-rows for one t. 256 threads.
// ---------------------------------------------------------------------------
__global__ __launch_bounds__(256) void gate2_softmax(
    const unsigned short* __restrict__ gh, const float* __restrict__ W2,
    const float* __restrict__ b2, float* __restrict__ gw)
{
    const int t = blockIdx.y;
    const long b0 = (long)blockIdx.x * 64;
    const int tid = threadIdx.x;
    __shared__ __align__(16) unsigned short ghs[64 * 256];
    __shared__ float ls[64 * 16];
    #pragma unroll
    for (int it = 0; it < 8; ++it) {
        int seg = it * 256 + tid;
        int row = seg >> 5;
        int col = (seg & 31) * 8;
        *(uint4*)&ghs[seg * 8] =
            *(const uint4*)&gh[(b0 + row) * (T_N * GH_N) + (long)t * GH_N + col];
    }
    __syncthreads();
    const float* W2t = W2 + (long)t * GH_N * K16;
    #pragma unroll
    for (int it = 0; it < 4; ++it) {
        int o = it * 256 + tid;
        int b = o >> 4, k = o & 15;
        float acc = b2[t * K16 + k];
        #pragma unroll 8
        for (int h = 0; h < GH_N; ++h)
            acc += bf2f(ghs[b * 256 + h]) * W2t[h * K16 + k];
        ls[o] = acc;
    }
    __syncthreads();
    if (tid < 64) {
        float m = -1e30f;
        #pragma unroll
        for (int k = 0; k < 16; ++k) m = fmaxf(m, ls[tid * 16 + k]);
        float e[16], s = 0.f;
        #pragma unroll
        for (int k = 0; k < 16; ++k) { e[k] = expf(ls[tid * 16 + k] - m); s += e[k]; }
        const float inv = 1.0f / s;
        float* gwp = gw + (b0 + tid) * (T_N * K16) + (long)t * K16;
        #pragma unroll
        for (int k = 0; k < 16; ++k) gwp[k] = e[k] * inv;
    }
}

// ---------------------------------------------------------------------------
// agg: aggb[t][b][e] = bf16( sum_k gw[b][t][k] * emb[b][k*256+e] )
// Block 256 thr = 8 rows x 32 thr; each thread covers 8 e-cols.
// ---------------------------------------------------------------------------
__global__ __launch_bounds__(256) void agg_kernel(
    const unsigned short* __restrict__ emb, const float* __restrict__ gw,
    unsigned short* __restrict__ aggb, long bc)
{
    const long b = (long)blockIdx.x * 8 + (threadIdx.x >> 5);
    const int e0 = (threadIdx.x & 31) * 8;
    const unsigned short* er = emb + b * 4096 + e0;
    const float* gwr = gw + b * 48;
    float a0[8] = {}, a1[8] = {}, a2[8] = {};
    #pragma unroll
    for (int k = 0; k < 16; ++k) {
        short8 v = *(const short8*)(er + (long)k * 256);
        const float w0 = gwr[k], w1 = gwr[16 + k], w2 = gwr[32 + k];
        #pragma unroll
        for (int j = 0; j < 8; ++j) {
            float f = bf2f((unsigned short)v[j]);
            a0[j] += w0 * f; a1[j] += w1 * f; a2[j] += w2 * f;
        }
    }
    unsigned r0[4] = {pack2(a0[0], a0[1]), pack2(a0[2], a0[3]),
                      pack2(a0[4], a0[5]), pack2(a0[6], a0[7])};
    unsigned r1[4] = {pack2(a1[0], a1[1]), pack2(a1[2], a1[3]),
                      pack2(a1[4], a1[5]), pack2(a1[6], a1[7])};
    unsigned r2[4] = {pack2(a2[0], a2[1]), pack2(a2[2], a2[3]),
                      pack2(a2[4], a2[5]), pack2(a2[6], a2[7])};
    *(uint4*)(aggb + 0L * bc * 256 + b * 256 + e0) = *(uint4*)r0;
    *(uint4*)(aggb + 1L * bc * 256 + b * 256 + e0) = *(uint4*)r1;
    *(uint4*)(aggb + 2L * bc * 256 + b * 256 + e0) = *(uint4*)r2;
}

// ---------------------------------------------------------------------------
// tower_fused (per t): th = relu(agg·W1+b1) [MFMA], out = th·W2+b2 [MFMA]
// Block: 128 rows; stage1 = 128x128xK256; th via LDS; stage2 = 128x64xK128.
// ---------------------------------------------------------------------------
__global__ __launch_bounds__(256) void tower_fused(
    const unsigned short* __restrict__ aggb, long bc,
    const unsigned short* __restrict__ w1t, const float* __restrict__ tb1,
    const unsigned short* __restrict__ w2t, const float* __restrict__ tb2,
    float* __restrict__ out)
{
    __shared__ __align__(16) unsigned short sm[24576];   // 48 KB
    unsigned short* As  = sm;            // [128*32]   (stage 1 staging)
    unsigned short* Bs  = sm + 4096;     // [128*32]
    unsigned short* th  = sm;            // [128*128]  (reused after stage 1)
    unsigned short* w2s = sm + 16384;    // [64*128]
    const int tid = threadIdx.x;
    const int t = blockIdx.y;
    const long m0 = (long)blockIdx.x * 128;
    const unsigned short* Ab = aggb + (long)t * bc * 256 + m0 * 256;
    const unsigned short* Bb = w1t + (long)t * (TH_N * E_N);
    const int lane16 = tid & 15;
    const int quad = (tid & 63) >> 4;
    const int wave = tid >> 6;
    const int wm = (wave >> 1) * 64;
    const int wn = (wave & 1) * 64;
    const int srow = tid >> 2;
    const int scol = (tid & 3) * 8;

    // W2 tile [64][128] bf16 -> LDS (region disjoint from staging)
    #pragma unroll
    for (int i = 0; i < 4; ++i)
        *(uint4*)&w2s[(i * 256 + tid) * 8] =
            *(const uint4*)&w2t[(long)t * (TO_N * TH_N) + (long)(i * 256 + tid) * 8];

    // ---- stage 1: [128x256]@[256x128] ----
    floatx4 acc[4][4] = {};
    for (int k0 = 0; k0 < 256; k0 += 32) {
#if HAVE_GLL
        load_lds16(Ab + (long)srow * 256 + k0 + scol, &As[tid * 8]);
        load_lds16(Ab + (long)(srow + 64) * 256 + k0 + scol, &As[2048 + tid * 8]);
        load_lds16(Bb + (long)srow * 256 + k0 + scol, &Bs[tid * 8]);
        load_lds16(Bb + (long)(srow + 64) * 256 + k0 + scol, &Bs[2048 + tid * 8]);
#else
        *(uint4*)&As[tid * 8] = *(const uint4*)(Ab + (long)srow * 256 + k0 + scol);
        *(uint4*)&As[2048 + tid * 8] = *(const uint4*)(Ab + (long)(srow + 64) * 256 + k0 + scol);
        *(uint4*)&Bs[tid * 8] = *(const uint4*)(Bb + (long)srow * 256 + k0 + scol);
        *(uint4*)&Bs[2048 + tid * 8] = *(const uint4*)(Bb + (long)(srow + 64) * 256 + k0 + scol);
#endif
        __syncthreads();
        short8 a[4], b[4];
        #pragma unroll
        for (int mi = 0; mi < 4; ++mi)
            a[mi] = *(const short8*)&As[(wm + mi * 16 + lane16) * 32 + quad * 8];
        #pragma unroll
        for (int ni = 0; ni < 4; ++ni)
            b[ni] = *(const short8*)&Bs[(wn + ni * 16 + lane16) * 32 + quad * 8];
        #pragma unroll
        for (int mi = 0; mi < 4; ++mi)
            #pragma unroll
            for (int ni = 0; ni < 4; ++ni)
                acc[mi][ni] = __builtin_amdgcn_mfma_f32_16x16x32_bf16(
                    a[mi], b[ni], acc[mi][ni], 0, 0, 0);
        __syncthreads();
    }

    // epilogue 1: bias+relu -> th LDS [row][col] bf16
    #pragma unroll
    for (int mi = 0; mi < 4; ++mi) {
        #pragma unroll
        for (int ni = 0; ni < 4; ++ni) {
            const int col = wn + ni * 16 + lane16;
            const float bv = tb1[t * TH_N + col];
            #pragma unroll
            for (int r = 0; r < 4; ++r) {
                const int row = wm + mi * 16 + quad * 4 + r;
                th[row * 128 + col] = f2bf(fmaxf(acc[mi][ni][r] + bv, 0.0f));
            }
        }
    }
    __syncthreads();

    // ---- stage 2: [128x128]@[128x64] -> out ----
    floatx4 acc2[2][4] = {};
    #pragma unroll
    for (int kk = 0; kk < 4; ++kk) {
        short8 a2[2], b2[4];
        #pragma unroll
        for (int mi = 0; mi < 2; ++mi)
            a2[mi] = *(const short8*)&th[(wave * 32 + mi * 16 + lane16) * 128 + kk * 32 + quad * 8];
        #pragma unroll
        for (int ni = 0; ni < 4; ++ni)
            b2[ni] = *(const short8*)&w2s[(ni * 16 + lane16) * 128 + kk * 32 + quad * 8];
        #pragma unroll
        for (int mi = 0; mi < 2; ++mi)
            #pragma unroll
            for (int ni = 0; ni < 4; ++ni)
                acc2[mi][ni] = __builtin_amdgcn_mfma_f32_16x16x32_bf16(
                    a2[mi], b2[ni], acc2[mi][ni], 0, 0, 0);
    }
    #pragma unroll
    for (int mi = 0; mi < 2; ++mi) {
        #pragma unroll
        for (int ni = 0; ni < 4; ++ni) {
            const int col = ni * 16 + lane16;
            const float bv = tb2[t * TO_N + col];
            #pragma unroll
            for (int r = 0; r < 4; ++r) {
                const int row = wave * 32 + mi * 16 + quad * 4 + r;
                out[(m0 + row) * (T_N * TO_N) + t * TO_N + col] = acc2[mi][ni][r] + bv;
            }
        }
    }
}

// ---------------------------------------------------------------------------
extern "C" void kernel_launch(void* const* d_in, const int* in_sizes, int n_in,
                              void* d_out, int out_size, void* d_ws, size_t ws_size,
                              hipStream_t stream)
{
    const float* x   = (const float*)d_in[0];
    const float* eW1 = (const float*)d_in[1];
    const float* eb1 = (const float*)d_in[2];
    const float* eW2 = (const float*)d_in[3];
    const float* eb2 = (const float*)d_in[4];
    const float* gW1 = (const float*)d_in[5];
    const float* gb1 = (const float*)d_in[6];
    const float* gW2 = (const float*)d_in[7];
    const float* gb2 = (const float*)d_in[8];
    const float* tW1 = (const float*)d_in[9];
    const float* tb1 = (const float*)d_in[10];
    const float* tW2 = (const float*)d_in[11];
    const float* tb2 = (const float*)d_in[12];
    float* out = (float*)d_out;

    char* ws = (char*)d_ws;
    // Persistent weight buffers (bf16, transposed): 13,615,104 B total
    unsigned short* W1t  = (unsigned short*)(ws + 0);          // [16][512][512]
    unsigned short* W2t  = (unsigned short*)(ws + 8388608);    // [16][256][512]
    unsigned short* G1t  = (unsigned short*)(ws + 12582912);   // [3][256][512]
    unsigned short* TW1t = (unsigned short*)(ws + 13369344);   // [3][128][256]
    unsigned short* TW2t = (unsigned short*)(ws + 13565952);   // [3][64][128]
    const size_t WFIX = 13615104;

    // Per-chunk scratch: 35,008 B per batch row; largest chunk that fits.
    const long per_row = 35008;
    long BC = 0;
    for (long cand = 16384; cand >= 256; cand >>= 1) {
        if (WFIX + (size_t)(cand * per_row) <= ws_size) { BC = cand; break; }
    }
    if (BC == 0) return;  // workspace too small — fail cleanly

    char* p = ws + WFIX;
    unsigned short* xb   = (unsigned short*)p; p += BC * 2048 * 2;  // [BC][G*D]
    unsigned short* ginb = (unsigned short*)p; p += BC * 1536 * 2;  // [BC][T*D]
    unsigned short* h1   = (unsigned short*)p; p += BC * 8192 * 2;  // [BC][16*H]
    unsigned short* embb = (unsigned short*)p; p += BC * 4096 * 2;  // [BC][16*E]
    unsigned short* gh   = (unsigned short*)p; p += BC * 768 * 2;   // [BC][T*GH]
    float*          gw   = (float*)p;          p += BC * 48 * 4;    // [BC][T][16]
    unsigned short* aggb = (unsigned short*)p;                      // [3][BC][256]

    // Weight transposes (once per call)
    transpose_w<<<dim3(16, 16, 16), dim3(32, 8), 0, stream>>>(eW1, W1t, 512, 512);
    transpose_w<<<dim3(8, 16, 16), dim3(32, 8), 0, stream>>>(eW2, W2t, 512, 256);
    transpose_w<<<dim3(8, 16, 3), dim3(32, 8), 0, stream>>>(gW1, G1t, 512, 256);
    transpose_w<<<dim3(4, 8, 3), dim3(32, 8), 0, stream>>>(tW1, TW1t, 256, 128);
    transpose_w<<<dim3(2, 4, 3), dim3(32, 8), 0, stream>>>(tW2, TW2t, 128, 64);

    const long n_chunks = B_N / BC;
    for (long c = 0; c < n_chunks; ++c) {
        const float* xc = x + c * BC * (G_N * D_N);
        float* outc = out + c * BC * (T_N * TO_N);

        convert_inputs<<<BC, 256, 0, stream>>>(xc, xb, ginb);
        // expert layer 1: per g: [BC x 512] @ [512 x 2048] -> relu -> h1 (bf16)
        gemm_bf16<1><<<dim3(BC / 128, 16, 4), 256, 0, stream>>>(
            xb, 2048, 512, W1t, 1048576, eb1, 2048, h1, 8192, 2048, 512);
        // gate layer 1: per t: [BC x 512] @ [512 x 256] -> relu -> gh (bf16)
        gemm_bf16<1><<<dim3(BC / 128, 2, 3), 256, 0, stream>>>(
            ginb, 1536, 512, G1t, 131072, gb1, 256, gh, 768, 256, 512);
        // gate layer 2 + softmax -> gw (fp32)
        gate2_softmax<<<dim3(BC / 64, 3), 256, 0, stream>>>(gh, gW2, gb2, gw);
        // expert layer 2: per (g,n): [BC x 512] @ [512 x 256] -> emb (bf16)
        gemm_bf16<0><<<dim3(BC / 128, 2, 16), 256, 0, stream>>>(
            h1, 8192, 512, W2t, 131072, eb2, 256, embb, 4096, 256, 512);
        // agg -> aggb bf16 [3][BC][256]
        agg_kernel<<<BC / 8, 256, 0, stream>>>(embb, gw, aggb, BC);
        // towers (MFMA, fused both layers) -> out fp32
        tower_fused<<<dim3(BC / 128, 3), 256, 0, stream>>>(
            aggb, BC, TW1t, tb1, TW2t, tb2, outc);
    }
}